// Round 13
// baseline (111.737 us; speedup 1.0000x reference)
//
#include <hip/hip_runtime.h>
#include <math.h>

#define NQ    14
#define DIM   16384
#define DEPTH 4

// Packed-fp32 complex: f2 = (re, im) -> v_pk_fma_f32 (2 FLOP/instr, 4 cyc;
// same FLOP rate as scalar but half the instruction stream — r11/r12 cycle
// accounting).
typedef __attribute__((ext_vector_type(2))) float f2;
typedef __attribute__((ext_vector_type(4))) float f4;

__device__ __forceinline__ f2 cmul(f2 a, f2 b) {
    return (f2){a.x*b.x - a.y*b.y, a.x*b.y + a.y*b.x};
}
// out = u*x + v*y (complex), pre-swapped forms us=(-u.i,u.r): 1 pk_mul + 3 pk_fma
__device__ __forceinline__ f2 cmac2(f2 x, f2 u, f2 us, f2 y, f2 v, f2 vs) {
    f2 r = x.xx * u;
    r += x.yy * us;
    r += y.xx * v;
    r += y.yy * vs;
    return r;
}

// ---------------- register-resident state, two views (HW-verified r10) -----
// n = t&63, w = t>>6. Qubit q <-> amplitude bit e[13-q].
// View A: e13..e10 = l3..l0 (q0-3 reg); e9..e4 = n5..n0; e3..e0 = w.
//   A gates: q0-3 reg(8,4,2,1), q6 (xor8), q8 (xor2), q9 (xor1).
// View B: e3..e0 = l3..l0 (q10-13 reg); e13..e10 = w;
//         e9=n3, e8=n1, e7=n5, e6=n0, e5=n4, e4=n2.
//   B gates: q10-13 reg(8,4,2,1), q4 (xor8), q5 (xor2), q7 (xor1).
//
// r13: WAVE-ROTATED gate schedule. All 7 gates of a half-layer are wave-local
// (reg butterflies + DPP) and act on distinct qubits -> they commute and may
// be applied in any per-wave order. Wave w starts at slot w%7, so the 4 waves
// sharing a SIMD stall on DIFFERENT gates' coefficient loads at different
// times — removing the lockstep lgkm gaps that pinned VALU duty at ~54%
// (r12 cycle model: ~290 cyc compute vs ~120 cyc aligned stall per gate).
//
// Remap LDS layout: L(e) = e[7:4] | (e[9:8]<<4) | (e[3:0]<<6) | (e[13:10]<<10)
//   A-side: t + (l<<10);  B-side: baseB + (l<<6). Conflict-free both sides.
//   One barrier per remap (store set == own previous read set; verified r11).

// ---- cross-lane exchanges (all DPP = pure VALU) ----
template<int CTRL>
__device__ __forceinline__ f2 dpp2(f2 v) {
    union U { f2 f; int i[2]; } u, r;
    u.f = v;
    r.i[0] = __builtin_amdgcn_update_dpp(0, u.i[0], CTRL, 0xF, 0xF, true);
    r.i[1] = __builtin_amdgcn_update_dpp(0, u.i[1], CTRL, 0xF, 0xF, true);
    return r.f;
}
template<int XB> __device__ __forceinline__ f2 lxchg(f2 v);
template<> __device__ __forceinline__ f2 lxchg<1>(f2 v) { return dpp2<0xB1>(v); }   // quad_perm [1,0,3,2]
template<> __device__ __forceinline__ f2 lxchg<2>(f2 v) { return dpp2<0x4E>(v); }   // quad_perm [2,3,0,1]
template<> __device__ __forceinline__ f2 lxchg<8>(f2 v) { return dpp2<0x128>(v); }  // row_ror:8 == xor8

// Register-qubit gate over 16 amps: butterfly across amp-index bit MASK.
template<int MASK>
__device__ __forceinline__ void reg_gate(f2 a[16], const f4* G) {
    f4 g0 = G[0], g1 = G[1], g2 = G[2], g3 = G[3];
    #pragma unroll
    for (int l = 0; l < 16; ++l) {
        if (l & MASK) continue;
        const int j = l | MASK;
        f2 x = a[l], y = a[j];
        a[l] = cmac2(x, g0.xy, g0.zw, y, g1.xy, g1.zw);
        a[j] = cmac2(x, g2.xy, g2.zw, y, g3.xy, g3.zw);
    }
}

// Lane-qubit gate: DPP exchange; each lane computes its own half.
// lo lane: rows 0,1 = (u00,u01); hi lane: rows 3,2 = (u11,u10).
template<int XB>
__device__ __forceinline__ void lane_gate(f2 a[16], const f4* G, int t) {
    const bool hi = (t & XB) != 0;
    f4 c1 = G[hi ? 3 : 0];
    f4 c2 = G[hi ? 2 : 1];
    #pragma unroll
    for (int l = 0; l < 16; ++l) {
        f2 p = lxchg<XB>(a[l]);
        a[l] = cmac2(a[l], c1.xy, c1.zw, p, c2.xy, c2.zw);
    }
}

// CZ sign in view A: e = (l<<10)|(n<<4)|w.  (HW-verified r10)
__device__ __forceinline__ void cz_A(f2 a[16], int t) {
    const int n = t & 63, w = t >> 6;
    const int pT = (__popc(w & (w >> 1)) + __popc(n & (n >> 1)) + ((n & 1) & (w >> 3))) & 1;
    const float F0 = pT ? -1.f : 1.f;
    const float F1 = (pT ^ ((n >> 5) & 1)) ? -1.f : 1.f;
    #pragma unroll
    for (int l = 0; l < 16; ++l) {
        float s = (l & 1) ? F1 : F0;                 // cross term l0 & n5
        if (__popc(l & (l >> 1)) & 1) s = -s;        // compile-time per l
        a[l] *= s;
    }
}

// CZ sign in view B: e9=n3,e8=n1,e7=n5,e6=n0,e5=n4,e4=n2.  (HW-verified r10)
__device__ __forceinline__ void cz_B(f2 a[16], int t) {
    const int n = t & 63, w = t >> 6;
    const int n0 = n & 1, n1 = (n >> 1) & 1, n2 = (n >> 2) & 1;
    const int n3 = (n >> 3) & 1, n4 = (n >> 4) & 1, n5 = (n >> 5) & 1;
    const int pT = ((n2 & n4) ^ (n4 & n0) ^ (n0 & n5) ^ (n5 & n1) ^ (n1 & n3)
                    ^ (n3 & (w & 1)) ^ (__popc(w & (w >> 1)) & 1));
    const float F0 = pT ? -1.f : 1.f;
    const float F1 = (pT ^ n2) ? -1.f : 1.f;
    #pragma unroll
    for (int l = 0; l < 16; ++l) {
        float s = (l & 8) ? F1 : F0;                 // cross term l3 & n2
        if (__popc(l & (l >> 1)) & 1) s = -s;        // compile-time per l
        a[l] *= s;
    }
}

__global__ __launch_bounds__(1024)
void qlg_kernel(const float* __restrict__ cond,
                const float* __restrict__ Wenc,
                const float* __restrict__ benc,
                const float* __restrict__ wts,
                float* __restrict__ out)
{
    __shared__ f2 st[DIM];                  // 128 KB remap buffer (L-layout)
    __shared__ f4 gtab[6][7][4];            // schedule-ordered gate table
    __shared__ f4 gates0[NQ][2];            // layer-0 gates (for stage 2 only)
    __shared__ f2 qv[NQ][2];
    __shared__ f2 Phi[128];
    __shared__ f2 Plo[128];
    __shared__ float embS[NQ];
    __shared__ float wred[16][NQ];
    __shared__ float lat[NQ];

    const int b = blockIdx.x;
    const int t = threadIdx.x;
    const int n = t & 63, w = t >> 6;
    const int bB = (w << 10)
                 | (((n >> 3) & 1) << 5) | (((n >> 1) & 1) << 4)
                 | (((n >> 5) & 1) << 3) | ((n & 1) << 2)
                 | (((n >> 4) & 1) << 1) | ((n >> 2) & 1);
    const int wrot = w % 7;                 // per-wave schedule rotation

    // ---- stage 1: embedding (SiLU) + gate matrices into the schedule ----
    if (t < NQ) {
        float s = benc[t];
        #pragma unroll
        for (int k = 0; k < NQ; ++k) s += cond[b*NQ + k] * Wenc[t*NQ + k];
        embS[t] = s / (1.0f + __expf(-s));
    }
    if (t >= 64 && t < 64 + DEPTH*NQ) {
        const int gi = t - 64;
        const int d = gi / NQ, ww = gi % NQ;
        const float p0 = wts[(d*NQ + ww)*3 + 0];
        const float p1 = wts[(d*NQ + ww)*3 + 1];
        const float p2 = wts[(d*NQ + ww)*3 + 2];
        float s0, c0, s1, c1, s2, c2;
        sincosf(0.5f*p0, &s0, &c0);
        sincosf(0.5f*p1, &s1, &c1);
        sincosf(0.5f*p2, &s2, &c2);
        // U = RY(p2) * RX(p1) * RZ(p0)
        f2 e0  = (f2){c0, -s0};
        f2 e0c = (f2){c0,  s0};
        f2 is1 = (f2){0.f, -s1};
        f2 m00 = c1 * e0;
        f2 m01 = cmul(is1, e0c);
        f2 m10 = cmul(is1, e0);
        f2 m11 = c1 * e0c;
        f2 u00 = c2*m00 - s2*m10;
        f2 u01 = c2*m01 - s2*m11;
        f2 u10 = s2*m00 + c2*m10;
        f2 u11 = s2*m01 + c2*m11;
        if (d == 0) {
            gates0[ww][0] = (f4){u00.x, u00.y, u01.x, u01.y};
            gates0[ww][1] = (f4){u10.x, u10.y, u11.x, u11.y};
        } else {
            // half-layers h0..h5 = (1,A),(1,B),(2,B),(2,A),(3,A),(3,B);
            // slot order: A: q0,q1,q2,q3,q6,q8,q9   B: q10,q11,q12,q13,q4,q5,q7
            const bool isA = (ww <= 3) || (ww == 6) || (ww == 8) || (ww == 9);
            int slot;
            if (isA) slot = (ww <= 3) ? ww : (ww == 6 ? 4 : (ww == 8 ? 5 : 6));
            else     slot = (ww >= 10) ? (ww - 10) : (ww == 4 ? 4 : (ww == 5 ? 5 : 6));
            const int h = (d == 1) ? (isA ? 0 : 1)
                        : (d == 2) ? (isA ? 3 : 2)
                                   : (isA ? 4 : 5);
            gtab[h][slot][0] = (f4){u00.x, u00.y, -u00.y, u00.x};
            gtab[h][slot][1] = (f4){u01.x, u01.y, -u01.y, u01.x};
            gtab[h][slot][2] = (f4){u10.x, u10.y, -u10.y, u10.x};
            gtab[h][slot][3] = (f4){u11.x, u11.y, -u11.y, u11.x};
        }
    }
    __syncthreads();

    // ---- stage 2: per-wire 2-vectors after encoding + layer 0 ----
    if (t < NQ) {
        float v = embS[t];
        float s, c;
        sincosf(0.5f*v, &s, &c);
        f2 a0 = (f2){c*c,  s*s};
        f2 a1 = (f2){s*c, -s*c};
        f4 va = gates0[t][0], vb = gates0[t][1];
        f2 u00 = (f2){va.x, va.y}, u01 = (f2){va.z, va.w};
        f2 u10 = (f2){vb.x, vb.y}, u11 = (f2){vb.z, vb.w};
        qv[t][0] = cmul(u00, a0) + cmul(u01, a1);
        qv[t][1] = cmul(u10, a0) + cmul(u11, a1);
    }
    __syncthreads();

    // ---- stage 3: partial-product tables ----
    if (t < 128) {
        f2 p = qv[0][(t >> 6) & 1];
        #pragma unroll
        for (int ww = 1; ww <= 6; ++ww) p = cmul(p, qv[ww][(t >> (6 - ww)) & 1]);
        Phi[t] = p;
    } else if (t < 256) {
        const int j = t - 128;
        f2 p = qv[7][(j >> 6) & 1];
        #pragma unroll
        for (int ww = 8; ww <= 13; ++ww) p = cmul(p, qv[ww][(j >> (13 - ww)) & 1]);
        Plo[j] = p;
    }
    __syncthreads();

    // ---- stage 4: build product state IN REGISTERS (view A), CZ0 fused ----
    f2 a[16];
    {
        f2 plo = Plo[((n & 7) << 4) | w];
        #pragma unroll
        for (int l = 0; l < 16; ++l)
            a[l] = cmul(Phi[(l << 3) | (n >> 3)], plo);
        cz_A(a, t);
    }

    // ---- stage 5: 6 half-layers; per-wave rotated gate order ----
    #pragma unroll 1
    for (int h = 0; h < 6; ++h) {
        const f4 (*g)[4] = gtab[h];
        #pragma unroll 1
        for (int k = 0; k < 7; ++k) {
            int slot = k + wrot; if (slot >= 7) slot -= 7;
            switch (slot) {
                case 0: reg_gate<8>(a, g[0]); break;
                case 1: reg_gate<4>(a, g[1]); break;
                case 2: reg_gate<2>(a, g[2]); break;
                case 3: reg_gate<1>(a, g[3]); break;
                case 4: lane_gate<8>(a, g[4], t); break;
                case 5: lane_gate<2>(a, g[5], t); break;
                default: lane_gate<1>(a, g[6], t); break;
            }
        }
        if (h == 1)      cz_B(a, t);   // CZ after layer 1 (view B)
        else if (h == 3) cz_A(a, t);   // CZ after layer 2 (view A)
        if (h == 0 || h == 4) {        // remap A -> B
            #pragma unroll
            for (int l = 0; l < 16; ++l) st[t + (l << 10)] = a[l];
            __syncthreads();
            #pragma unroll
            for (int l = 0; l < 16; ++l) a[l] = st[bB + (l << 6)];
        } else if (h == 2) {           // remap B -> A
            #pragma unroll
            for (int l = 0; l < 16; ++l) st[bB + (l << 6)] = a[l];
            __syncthreads();
            #pragma unroll
            for (int l = 0; l < 16; ++l) a[l] = st[t + (l << 10)];
        }
    }
    // (CZ after layer 3 dropped: |psi|^2 invariant)

    // ---- fused probability reduction (view B) ----
    float SU, Q10, Q11, Q12, Q13;
    {
        SU = Q10 = Q11 = Q12 = Q13 = 0.f;
        #pragma unroll
        for (int l = 0; l < 16; ++l) {
            float p = a[l].x*a[l].x + a[l].y*a[l].y;
            SU  += p;
            Q10 += (l & 8) ? -p : p;    // q10 <-> e3 = l3
            Q11 += (l & 4) ? -p : p;
            Q12 += (l & 2) ? -p : p;
            Q13 += (l & 1) ? -p : p;
        }
    }

    // ---- stage 6: reduce to 14 expectations, layernorm ----
    // View-B sign bit (thread-uniform) for wire ww in 0..9:
    // q0:t9 q1:t8 q2:t7 q3:t6 q4:t3 q5:t1 q6:t5 q7:t0 q8:t4 q9:t2.
    {
        const int lane = t & 63, wv = t >> 6;
        const int sbit[10] = {9, 8, 7, 6, 3, 1, 5, 0, 4, 2};
        #pragma unroll
        for (int ww = 0; ww < NQ; ++ww) {
            float v;
            if      (ww == 10) v = Q10;
            else if (ww == 11) v = Q11;
            else if (ww == 12) v = Q12;
            else if (ww == 13) v = Q13;
            else               v = ((t >> sbit[ww]) & 1) ? -SU : SU;
            #pragma unroll
            for (int off = 32; off > 0; off >>= 1) v += __shfl_down(v, off, 64);
            if (lane == 0) wred[wv][ww] = v;
        }
    }
    __syncthreads();
    if (t < NQ) {
        float s = 0.f;
        #pragma unroll
        for (int k = 0; k < 16; ++k) s += wred[k][t];
        lat[t] = s;
    }
    __syncthreads();
    if (t < NQ) {
        float mu = 0.f;
        #pragma unroll
        for (int k = 0; k < NQ; ++k) mu += lat[k];
        mu *= (1.0f / NQ);
        float var = 0.f;
        #pragma unroll
        for (int k = 0; k < NQ; ++k) { float dv = lat[k] - mu; var += dv*dv; }
        var *= (1.0f / NQ);
        out[b*NQ + t] = (lat[t] - mu) * rsqrtf(var + 1e-5f);
    }
}

extern "C" void kernel_launch(void* const* d_in, const int* in_sizes, int n_in,
                              void* d_out, int out_size, void* d_ws, size_t ws_size,
                              hipStream_t stream)
{
    (void)n_in; (void)d_ws; (void)ws_size; (void)out_size;
    const float* cond = (const float*)d_in[0];
    const float* Wenc = (const float*)d_in[1];
    const float* benc = (const float*)d_in[2];
    const float* wts  = (const float*)d_in[3];
    float* out = (float*)d_out;
    const int B = in_sizes[0] / NQ;   // 256
    qlg_kernel<<<dim3(B), dim3(1024), 0, stream>>>(cond, Wenc, benc, wts, out);
}

// Round 14
// 93.700 us; speedup vs baseline: 1.1925x; 1.1925x over previous
//
#include <hip/hip_runtime.h>
#include <math.h>

#define NQ    14
#define DIM   16384
#define DEPTH 4

// Packed-fp32 complex: f2 = (re, im) -> v_pk_fma_f32 (2 FLOP/instr, 4 cyc).
typedef __attribute__((ext_vector_type(2))) float f2;
typedef __attribute__((ext_vector_type(4))) float f4;

__device__ __forceinline__ f2 cmul(f2 a, f2 b) {
    return (f2){a.x*b.x - a.y*b.y, a.x*b.y + a.y*b.x};
}
// out = u*x + v*y (complex), pre-swapped forms us=(-u.i,u.r): 1 pk_mul + 3 pk_fma
__device__ __forceinline__ f2 cmac2(f2 x, f2 u, f2 us, f2 y, f2 v, f2 vs) {
    f2 r = x.xx * u;
    r += x.yy * us;
    r += y.xx * v;
    r += y.yy * vs;
    return r;
}

// ---------------- register-resident state, two views (HW-verified r10) -----
// n = t&63, w = t>>6. Qubit q <-> amplitude bit e[13-q].
// View A: e13..e10 = l3..l0 (q0-3 reg); e9..e4 = n5..n0; e3..e0 = w.
//   A gates: q0-3 reg(8,4,2,1), q6 (xor8), q8 (xor2), q9 (xor1).
// View B: e3..e0 = l3..l0 (q10-13 reg); e13..e10 = w;
//         e9=n3, e8=n1, e7=n5, e6=n0, e5=n4, e4=n2.
//   B gates: q10-13 reg(8,4,2,1), q4 (xor8), q5 (xor2), q7 (xor1).
//
// r14: gates are BATCH-INVARIANT (wts only) -> computed once by a 1-block
// prep kernel into d_ws; the main kernel reads them through a const
// __restrict__ pointer at wave-uniform addresses -> compiler emits scalar
// s_load (SMEM pipe) hoisted across the unrolled body, gates live in SGPRs.
// Removes the per-gate ds_read_b128 lgkm dependencies that (theory) kept all
// 4 barrier-synced waves/SIMD stalling at the same program points, and the
// 256x-redundant sincos gate prologue.
//
// Remap LDS layout: L(e) = e[7:4] | (e[9:8]<<4) | (e[3:0]<<6) | (e[13:10]<<10)
//   A-side: t + (l<<10);  B-side: baseB + (l<<6). Conflict-free both sides.
//   One barrier per remap (store set == own previous read set; verified r11).

// ---- cross-lane exchanges (all DPP = pure VALU) ----
template<int CTRL>
__device__ __forceinline__ f2 dpp2(f2 v) {
    union U { f2 f; int i[2]; } u, r;
    u.f = v;
    r.i[0] = __builtin_amdgcn_update_dpp(0, u.i[0], CTRL, 0xF, 0xF, true);
    r.i[1] = __builtin_amdgcn_update_dpp(0, u.i[1], CTRL, 0xF, 0xF, true);
    return r.f;
}
template<int XB> __device__ __forceinline__ f2 lxchg(f2 v);
template<> __device__ __forceinline__ f2 lxchg<1>(f2 v) { return dpp2<0xB1>(v); }   // quad_perm [1,0,3,2]
template<> __device__ __forceinline__ f2 lxchg<2>(f2 v) { return dpp2<0x4E>(v); }   // quad_perm [2,3,0,1]
template<> __device__ __forceinline__ f2 lxchg<8>(f2 v) { return dpp2<0x128>(v); }  // row_ror:8 == xor8

// Register-qubit gate over 16 amps: butterfly across amp-index bit MASK.
template<int MASK>
__device__ __forceinline__ void reg_gate(f2 a[16], const f4* __restrict__ G) {
    f4 g0 = G[0], g1 = G[1], g2 = G[2], g3 = G[3];
    #pragma unroll
    for (int l = 0; l < 16; ++l) {
        if (l & MASK) continue;
        const int j = l | MASK;
        f2 x = a[l], y = a[j];
        a[l] = cmac2(x, g0.xy, g0.zw, y, g1.xy, g1.zw);
        a[j] = cmac2(x, g2.xy, g2.zw, y, g3.xy, g3.zw);
    }
}

// Lane-qubit gate: DPP exchange; each lane computes its own half.
// lo lane: rows 0,1 = (u00,u01); hi lane: rows 3,2 = (u11,u10).
template<int XB>
__device__ __forceinline__ void lane_gate(f2 a[16], const f4* __restrict__ G, int t) {
    const bool hi = (t & XB) != 0;
    f4 c1 = G[hi ? 3 : 0];
    f4 c2 = G[hi ? 2 : 1];
    #pragma unroll
    for (int l = 0; l < 16; ++l) {
        f2 p = lxchg<XB>(a[l]);
        a[l] = cmac2(a[l], c1.xy, c1.zw, p, c2.xy, c2.zw);
    }
}

// CZ sign in view A: e = (l<<10)|(n<<4)|w.  (HW-verified r10)
__device__ __forceinline__ void cz_A(f2 a[16], int t) {
    const int n = t & 63, w = t >> 6;
    const int pT = (__popc(w & (w >> 1)) + __popc(n & (n >> 1)) + ((n & 1) & (w >> 3))) & 1;
    const float F0 = pT ? -1.f : 1.f;
    const float F1 = (pT ^ ((n >> 5) & 1)) ? -1.f : 1.f;
    #pragma unroll
    for (int l = 0; l < 16; ++l) {
        float s = (l & 1) ? F1 : F0;                 // cross term l0 & n5
        if (__popc(l & (l >> 1)) & 1) s = -s;        // compile-time per l
        a[l] *= s;
    }
}

// CZ sign in view B: e9=n3,e8=n1,e7=n5,e6=n0,e5=n4,e4=n2.  (HW-verified r10)
__device__ __forceinline__ void cz_B(f2 a[16], int t) {
    const int n = t & 63, w = t >> 6;
    const int n0 = n & 1, n1 = (n >> 1) & 1, n2 = (n >> 2) & 1;
    const int n3 = (n >> 3) & 1, n4 = (n >> 4) & 1, n5 = (n >> 5) & 1;
    const int pT = ((n2 & n4) ^ (n4 & n0) ^ (n0 & n5) ^ (n5 & n1) ^ (n1 & n3)
                    ^ (n3 & (w & 1)) ^ (__popc(w & (w >> 1)) & 1));
    const float F0 = pT ? -1.f : 1.f;
    const float F1 = (pT ^ n2) ? -1.f : 1.f;
    #pragma unroll
    for (int l = 0; l < 16; ++l) {
        float s = (l & 8) ? F1 : F0;                 // cross term l3 & n2
        if (__popc(l & (l >> 1)) & 1) s = -s;        // compile-time per l
        a[l] *= s;
    }
}

// ---- prep kernel: 42 variational gates + 14 layer-0 gates -> d_ws ----
// Layout (f4 units): [ (h*7+slot)*4 + row ] for h=0..5; [168 + ww*2 + row]
// for layer-0. Batch-invariant: runs once per launch (1 block).
__global__ void qlg_prep(const float* __restrict__ wts,
                         f4* __restrict__ G)
{
    const int t = threadIdx.x;
    if (t >= DEPTH * NQ) return;
    const int d = t / NQ, ww = t % NQ;
    const float p0 = wts[(d*NQ + ww)*3 + 0];
    const float p1 = wts[(d*NQ + ww)*3 + 1];
    const float p2 = wts[(d*NQ + ww)*3 + 2];
    float s0, c0, s1, c1, s2, c2;
    sincosf(0.5f*p0, &s0, &c0);
    sincosf(0.5f*p1, &s1, &c1);
    sincosf(0.5f*p2, &s2, &c2);
    // U = RY(p2) * RX(p1) * RZ(p0)
    f2 e0  = (f2){c0, -s0};
    f2 e0c = (f2){c0,  s0};
    f2 is1 = (f2){0.f, -s1};
    f2 m00 = c1 * e0;
    f2 m01 = cmul(is1, e0c);
    f2 m10 = cmul(is1, e0);
    f2 m11 = c1 * e0c;
    f2 u00 = c2*m00 - s2*m10;
    f2 u01 = c2*m01 - s2*m11;
    f2 u10 = s2*m00 + c2*m10;
    f2 u11 = s2*m01 + c2*m11;
    if (d == 0) {
        G[168 + ww*2 + 0] = (f4){u00.x, u00.y, u01.x, u01.y};
        G[168 + ww*2 + 1] = (f4){u10.x, u10.y, u11.x, u11.y};
    } else {
        // half-layers h0..h5 = (1,A),(1,B),(2,B),(2,A),(3,A),(3,B);
        // slot order: A: q0,q1,q2,q3,q6,q8,q9   B: q10,q11,q12,q13,q4,q5,q7
        const bool isA = (ww <= 3) || (ww == 6) || (ww == 8) || (ww == 9);
        int slot;
        if (isA) slot = (ww <= 3) ? ww : (ww == 6 ? 4 : (ww == 8 ? 5 : 6));
        else     slot = (ww >= 10) ? (ww - 10) : (ww == 4 ? 4 : (ww == 5 ? 5 : 6));
        const int h = (d == 1) ? (isA ? 0 : 1)
                    : (d == 2) ? (isA ? 3 : 2)
                               : (isA ? 4 : 5);
        const int base = (h*7 + slot)*4;
        G[base + 0] = (f4){u00.x, u00.y, -u00.y, u00.x};
        G[base + 1] = (f4){u01.x, u01.y, -u01.y, u01.x};
        G[base + 2] = (f4){u10.x, u10.y, -u10.y, u10.x};
        G[base + 3] = (f4){u11.x, u11.y, -u11.y, u11.x};
    }
}

__global__ __launch_bounds__(1024)
void qlg_kernel(const float* __restrict__ cond,
                const float* __restrict__ Wenc,
                const float* __restrict__ benc,
                const f4* __restrict__ gG,
                float* __restrict__ out)
{
    __shared__ f2 st[DIM];                  // 128 KB remap buffer (L-layout)
    __shared__ f2 qv[NQ][2];
    __shared__ f2 Phi[128];
    __shared__ f2 Plo[128];
    __shared__ float embS[NQ];
    __shared__ float wred[16][NQ];
    __shared__ float lat[NQ];

    const int b = blockIdx.x;
    const int t = threadIdx.x;
    const int n = t & 63, w = t >> 6;
    const int bB = (w << 10)
                 | (((n >> 3) & 1) << 5) | (((n >> 1) & 1) << 4)
                 | (((n >> 5) & 1) << 3) | ((n & 1) << 2)
                 | (((n >> 4) & 1) << 1) | ((n >> 2) & 1);

    // ---- stage 1: embedding (SiLU) only — gates come precomputed ----
    if (t < NQ) {
        float s = benc[t];
        #pragma unroll
        for (int k = 0; k < NQ; ++k) s += cond[b*NQ + k] * Wenc[t*NQ + k];
        float e = s / (1.0f + __expf(-s));
        embS[t] = e;
    }
    __syncthreads();

    // ---- stage 2: per-wire 2-vectors after encoding + layer 0 ----
    if (t < NQ) {
        float v = embS[t];
        float s, c;
        sincosf(0.5f*v, &s, &c);
        f2 a0 = (f2){c*c,  s*s};
        f2 a1 = (f2){s*c, -s*c};
        f4 va = gG[168 + t*2], vb = gG[168 + t*2 + 1];
        f2 u00 = (f2){va.x, va.y}, u01 = (f2){va.z, va.w};
        f2 u10 = (f2){vb.x, vb.y}, u11 = (f2){vb.z, vb.w};
        qv[t][0] = cmul(u00, a0) + cmul(u01, a1);
        qv[t][1] = cmul(u10, a0) + cmul(u11, a1);
    }
    __syncthreads();

    // ---- stage 3: partial-product tables ----
    if (t < 128) {
        f2 p = qv[0][(t >> 6) & 1];
        #pragma unroll
        for (int ww = 1; ww <= 6; ++ww) p = cmul(p, qv[ww][(t >> (6 - ww)) & 1]);
        Phi[t] = p;
    } else if (t < 256) {
        const int j = t - 128;
        f2 p = qv[7][(j >> 6) & 1];
        #pragma unroll
        for (int ww = 8; ww <= 13; ++ww) p = cmul(p, qv[ww][(j >> (13 - ww)) & 1]);
        Plo[j] = p;
    }
    __syncthreads();

    // ---- stage 4: build product state IN REGISTERS (view A), CZ0 fused ----
    f2 a[16];
    {
        f2 plo = Plo[((n & 7) << 4) | w];
        #pragma unroll
        for (int l = 0; l < 16; ++l)
            a[l] = cmul(Phi[(l << 3) | (n >> 3)], plo);
        cz_A(a, t);
    }

    // ---- stage 5: 6 half-layers (fully unrolled; gates via scalar loads) ----
    #pragma unroll
    for (int h = 0; h < 6; ++h) {
        const f4* __restrict__ g = gG + h*7*4;
        reg_gate<8>(a, g + 0*4);
        reg_gate<4>(a, g + 1*4);
        reg_gate<2>(a, g + 2*4);
        reg_gate<1>(a, g + 3*4);
        lane_gate<8>(a, g + 4*4, t);
        lane_gate<2>(a, g + 5*4, t);
        lane_gate<1>(a, g + 6*4, t);
        if (h == 1)      cz_B(a, t);   // CZ after layer 1 (view B)
        else if (h == 3) cz_A(a, t);   // CZ after layer 2 (view A)
        if (h == 0 || h == 4) {        // remap A -> B
            #pragma unroll
            for (int l = 0; l < 16; ++l) st[t + (l << 10)] = a[l];
            __syncthreads();
            #pragma unroll
            for (int l = 0; l < 16; ++l) a[l] = st[bB + (l << 6)];
        } else if (h == 2) {           // remap B -> A
            #pragma unroll
            for (int l = 0; l < 16; ++l) st[bB + (l << 6)] = a[l];
            __syncthreads();
            #pragma unroll
            for (int l = 0; l < 16; ++l) a[l] = st[t + (l << 10)];
        }
    }
    // (CZ after layer 3 dropped: |psi|^2 invariant)

    // ---- fused probability reduction (view B) ----
    float SU, Q10, Q11, Q12, Q13;
    {
        SU = Q10 = Q11 = Q12 = Q13 = 0.f;
        #pragma unroll
        for (int l = 0; l < 16; ++l) {
            float p = a[l].x*a[l].x + a[l].y*a[l].y;
            SU  += p;
            Q10 += (l & 8) ? -p : p;    // q10 <-> e3 = l3
            Q11 += (l & 4) ? -p : p;
            Q12 += (l & 2) ? -p : p;
            Q13 += (l & 1) ? -p : p;
        }
    }

    // ---- stage 6: reduce to 14 expectations, layernorm ----
    // View-B sign bit (thread-uniform) for wire ww in 0..9:
    // q0:t9 q1:t8 q2:t7 q3:t6 q4:t3 q5:t1 q6:t5 q7:t0 q8:t4 q9:t2.
    {
        const int lane = t & 63, wv = t >> 6;
        const int sbit[10] = {9, 8, 7, 6, 3, 1, 5, 0, 4, 2};
        #pragma unroll
        for (int ww = 0; ww < NQ; ++ww) {
            float v;
            if      (ww == 10) v = Q10;
            else if (ww == 11) v = Q11;
            else if (ww == 12) v = Q12;
            else if (ww == 13) v = Q13;
            else               v = ((t >> sbit[ww]) & 1) ? -SU : SU;
            #pragma unroll
            for (int off = 32; off > 0; off >>= 1) v += __shfl_down(v, off, 64);
            if (lane == 0) wred[wv][ww] = v;
        }
    }
    __syncthreads();
    if (t < NQ) {
        float s = 0.f;
        #pragma unroll
        for (int k = 0; k < 16; ++k) s += wred[k][t];
        lat[t] = s;
    }
    __syncthreads();
    if (t < NQ) {
        float mu = 0.f;
        #pragma unroll
        for (int k = 0; k < NQ; ++k) mu += lat[k];
        mu *= (1.0f / NQ);
        float var = 0.f;
        #pragma unroll
        for (int k = 0; k < NQ; ++k) { float dv = lat[k] - mu; var += dv*dv; }
        var *= (1.0f / NQ);
        out[b*NQ + t] = (lat[t] - mu) * rsqrtf(var + 1e-5f);
    }
}

extern "C" void kernel_launch(void* const* d_in, const int* in_sizes, int n_in,
                              void* d_out, int out_size, void* d_ws, size_t ws_size,
                              hipStream_t stream)
{
    (void)n_in; (void)ws_size; (void)out_size;
    const float* cond = (const float*)d_in[0];
    const float* Wenc = (const float*)d_in[1];
    const float* benc = (const float*)d_in[2];
    const float* wts  = (const float*)d_in[3];
    float* out = (float*)d_out;
    f4* G = (f4*)d_ws;                       // 196 f4 = 3136 B of workspace
    const int B = in_sizes[0] / NQ;          // 256
    qlg_prep<<<dim3(1), dim3(64), 0, stream>>>(wts, G);
    qlg_kernel<<<dim3(B), dim3(1024), 0, stream>>>(cond, Wenc, benc, G, out);
}

// Round 15
// 91.908 us; speedup vs baseline: 1.2157x; 1.0195x over previous
//
#include <hip/hip_runtime.h>
#include <hip/hip_fp16.h>
#include <math.h>

#define NQ    14
#define DIM   16384
#define DEPTH 4

typedef __attribute__((ext_vector_type(2))) float f2;
typedef __attribute__((ext_vector_type(4))) float f4;
typedef __half2 h2;

__device__ __forceinline__ f2 cmul(f2 a, f2 b) {
    return (f2){a.x*b.x - a.y*b.y, a.x*b.y + a.y*b.x};
}
__device__ __forceinline__ float czsgn(int e) {
    return (__popc(e & (e >> 1)) & 1) ? -1.0f : 1.0f;
}

// ---------------- fp16-plane state ----------------
// Same two views as r10-r14 (HW-verified). Amps paired by l0: pair k holds
// amps l=2k (lo half) and l=2k+1 (hi half) as re-plane hr[k] / im-plane hi[k]
// (__half2). v_pk_fma_f16 = 2 f16 FMA/lane in 2 cyc vs pk_f32's 4 cyc ->
// halves the 23.5us VALU floor. Reg gates with l-mask 8/4/2 = cross-pair
// (pair-mask 4/2/1, pure plane FMA); l-mask 1 = within-pair (half-swap +
// column-packed coeffs); lane gates = 1 DPP per plane. CZ = sign-bit XOR.
// Probabilities accumulate in fp32.

// complex butterfly on planes: (or,oi) = c1*x + c2*y
__device__ __forceinline__ void cfma2(h2 c1r, h2 c1i, h2 c2r, h2 c2i,
                                      h2 xr, h2 xi, h2 yr, h2 yi,
                                      h2& or_, h2& oi_)
{
    or_ = __hfma2(c1r, xr, __hfma2(__hneg2(c1i), xi,
          __hfma2(c2r, yr, __hmul2(__hneg2(c2i), yi))));
    oi_ = __hfma2(c1r, xi, __hfma2(c1i, xr,
          __hfma2(c2r, yi, __hmul2(c2i, yr))));
}

__device__ __forceinline__ h2 hxor(h2 v, unsigned m) {
    union { h2 h; unsigned u; } x; x.h = v; x.u ^= m; return x.h;
}

template<int CTRL>
__device__ __forceinline__ h2 dpph(h2 v) {
    union { h2 h; int i; } u, r;
    u.h = v;
    r.i = __builtin_amdgcn_update_dpp(0, u.i, CTRL, 0xF, 0xF, true);
    return r.h;
}
template<int XB> __device__ __forceinline__ h2 lx2(h2 v);
template<> __device__ __forceinline__ h2 lx2<1>(h2 v) { return dpph<0xB1>(v); }   // quad_perm [1,0,3,2]
template<> __device__ __forceinline__ h2 lx2<2>(h2 v) { return dpph<0x4E>(v); }   // quad_perm [2,3,0,1]
template<> __device__ __forceinline__ h2 lx2<8>(h2 v) { return dpph<0x128>(v); }  // row_ror:8 == xor8

// reg gate, cross-pair (pair-index mask KM in {4,2,1} <-> l-mask {8,4,2})
template<int KM>
__device__ __forceinline__ void reg_gate_h(h2 hr[8], h2 hi[8], const h2* __restrict__ g) {
    h2 c00r = g[0], c00i = g[1], c01r = g[2], c01i = g[3];
    h2 c10r = g[4], c10i = g[5], c11r = g[6], c11i = g[7];
    #pragma unroll
    for (int k = 0; k < 8; ++k) {
        if (k & KM) continue;
        const int j = k | KM;
        h2 xr = hr[k], xi = hi[k], yr = hr[j], yi = hi[j];
        cfma2(c00r, c00i, c01r, c01i, xr, xi, yr, yi, hr[k], hi[k]);
        cfma2(c10r, c10i, c11r, c11i, xr, xi, yr, yi, hr[j], hi[j]);
    }
}

// within-pair gate (l-mask 1): partner = swapped halves; coeffs column-packed
// A=(u00,u11), B=(u01,u10)
__device__ __forceinline__ void pair_gate_h(h2 hr[8], h2 hi[8], const h2* __restrict__ g) {
    h2 Ar = g[0], Ai = g[1], Br = g[2], Bi = g[3];
    #pragma unroll
    for (int k = 0; k < 8; ++k) {
        h2 pr = __lowhigh2highlow(hr[k]);
        h2 pi = __lowhigh2highlow(hi[k]);
        cfma2(Ar, Ai, Br, Bi, hr[k], hi[k], pr, pi, hr[k], hi[k]);
    }
}

// lane gate: DPP partner; per-lane row select (lo: u00,u01; hi: u11,u10)
template<int XB>
__device__ __forceinline__ void lane_gate_h(h2 hr[8], h2 hi[8], const h2* __restrict__ g, int t) {
    const bool hiL = (t & XB) != 0;
    h2 c1r = hiL ? g[6] : g[0];
    h2 c1i = hiL ? g[7] : g[1];
    h2 c2r = hiL ? g[4] : g[2];
    h2 c2i = hiL ? g[5] : g[3];
    #pragma unroll
    for (int k = 0; k < 8; ++k) {
        h2 pr = lx2<XB>(hr[k]);
        h2 pi = lx2<XB>(hi[k]);
        cfma2(c1r, c1i, c2r, c2i, hr[k], hi[k], pr, pi, hr[k], hi[k]);
    }
}

// CZ signs as sign-bit XOR. View A: e=(l<<10)|(n<<4)|w (verified r10).
__device__ __forceinline__ void cz_A_h(h2 hr[8], h2 hi[8], int t) {
    const int n = t & 63, w = t >> 6;
    const int pT = (__popc(w & (w >> 1)) + __popc(n & (n >> 1)) + ((n & 1) & (w >> 3))) & 1;
    const int f0 = pT, f1 = pT ^ ((n >> 5) & 1);   // F1: cross term l0 & n5
    #pragma unroll
    for (int k = 0; k < 8; ++k) {
        const int stlo = __popc((2*k) & ((2*k) >> 1)) & 1;
        const int sthi = __popc((2*k+1) & ((2*k+1) >> 1)) & 1;
        const unsigned mask = ((f0 ^ stlo) ? 0x8000u : 0u)
                            | ((f1 ^ sthi) ? 0x80000000u : 0u);
        hr[k] = hxor(hr[k], mask); hi[k] = hxor(hi[k], mask);
    }
}
// View B: e9=n3,e8=n1,e7=n5,e6=n0,e5=n4,e4=n2 (verified r10); cross = l3&n2.
__device__ __forceinline__ void cz_B_h(h2 hr[8], h2 hi[8], int t) {
    const int n = t & 63, w = t >> 6;
    const int n0 = n & 1, n1 = (n >> 1) & 1, n2 = (n >> 2) & 1;
    const int n3 = (n >> 3) & 1, n4 = (n >> 4) & 1, n5 = (n >> 5) & 1;
    const int pT = ((n2 & n4) ^ (n4 & n0) ^ (n0 & n5) ^ (n5 & n1) ^ (n1 & n3)
                    ^ (n3 & (w & 1)) ^ (__popc(w & (w >> 1)) & 1));
    const int f0 = pT, f1 = pT ^ n2;
    #pragma unroll
    for (int k = 0; k < 8; ++k) {
        const int fs = (k & 4) ? f1 : f0;           // l3 = k&4 selects F
        const int stlo = __popc((2*k) & ((2*k) >> 1)) & 1;
        const int sthi = __popc((2*k+1) & ((2*k+1) >> 1)) & 1;
        const unsigned mask = ((fs ^ stlo) ? 0x8000u : 0u)
                            | ((fs ^ sthi) ? 0x80000000u : 0u);
        hr[k] = hxor(hr[k], mask); hi[k] = hxor(hi[k], mask);
    }
}

// ---- prep: gates -> d_ws. h2 table (6 half-layers x 7 slots x 8 h2) at
// offset 0; layer-0 fp32 gates (f4 x 2 per wire) at offset 2048.
__global__ void qlg_prep(const float* __restrict__ wts, h2* __restrict__ Gh,
                         f4* __restrict__ G0)
{
    const int t = threadIdx.x;
    if (t >= DEPTH * NQ) return;
    const int d = t / NQ, ww = t % NQ;
    const float p0 = wts[(d*NQ + ww)*3 + 0];
    const float p1 = wts[(d*NQ + ww)*3 + 1];
    const float p2 = wts[(d*NQ + ww)*3 + 2];
    float s0, c0, s1, c1, s2, c2;
    sincosf(0.5f*p0, &s0, &c0);
    sincosf(0.5f*p1, &s1, &c1);
    sincosf(0.5f*p2, &s2, &c2);
    // U = RY(p2) * RX(p1) * RZ(p0)
    f2 e0  = (f2){c0, -s0};
    f2 e0c = (f2){c0,  s0};
    f2 is1 = (f2){0.f, -s1};
    f2 m00 = c1 * e0;
    f2 m01 = cmul(is1, e0c);
    f2 m10 = cmul(is1, e0);
    f2 m11 = c1 * e0c;
    f2 u00 = c2*m00 - s2*m10;
    f2 u01 = c2*m01 - s2*m11;
    f2 u10 = s2*m00 + c2*m10;
    f2 u11 = s2*m01 + c2*m11;
    if (d == 0) {
        G0[ww*2 + 0] = (f4){u00.x, u00.y, u01.x, u01.y};
        G0[ww*2 + 1] = (f4){u10.x, u10.y, u11.x, u11.y};
        return;
    }
    // half-layers h0..h5 = (1,A),(1,B),(2,B),(2,A),(3,A),(3,B);
    // slots: A: q0,q1,q2,q3,q6,q8,q9   B: q10,q11,q12,q13,q4,q5,q7
    const bool isA = (ww <= 3) || (ww == 6) || (ww == 8) || (ww == 9);
    int slot;
    if (isA) slot = (ww <= 3) ? ww : (ww == 6 ? 4 : (ww == 8 ? 5 : 6));
    else     slot = (ww >= 10) ? (ww - 10) : (ww == 4 ? 4 : (ww == 5 ? 5 : 6));
    const int h = (d == 1) ? (isA ? 0 : 1)
                : (d == 2) ? (isA ? 3 : 2)
                           : (isA ? 4 : 5);
    h2* g = Gh + (h*7 + slot)*8;
    if (slot == 3) {   // within-pair gate: column packing A=(u00,u11) B=(u01,u10)
        g[0] = __halves2half2(__float2half_rn(u00.x), __float2half_rn(u11.x));
        g[1] = __halves2half2(__float2half_rn(u00.y), __float2half_rn(u11.y));
        g[2] = __halves2half2(__float2half_rn(u01.x), __float2half_rn(u10.x));
        g[3] = __halves2half2(__float2half_rn(u01.y), __float2half_rn(u10.y));
        g[4] = g[5] = g[6] = g[7] = __float2half2_rn(0.f);
    } else {           // broadcast packing
        g[0] = __float2half2_rn(u00.x); g[1] = __float2half2_rn(u00.y);
        g[2] = __float2half2_rn(u01.x); g[3] = __float2half2_rn(u01.y);
        g[4] = __float2half2_rn(u10.x); g[5] = __float2half2_rn(u10.y);
        g[6] = __float2half2_rn(u11.x); g[7] = __float2half2_rn(u11.y);
    }
}

__global__ __launch_bounds__(1024)
void qlg_kernel(const float* __restrict__ cond,
                const float* __restrict__ Wenc,
                const float* __restrict__ benc,
                const h2* __restrict__ Gh,
                const f4* __restrict__ G0,
                float* __restrict__ out)
{
    __shared__ h2 st[DIM];                  // 64 KB remap buffer (f16 amps)
    __shared__ f2 qv[NQ][2];
    __shared__ f2 Phi[128];
    __shared__ f2 Plo[128];
    __shared__ float embS[NQ];
    __shared__ float wred[16][NQ];
    __shared__ float lat[NQ];

    const int b = blockIdx.x;
    const int t = threadIdx.x;
    const int n = t & 63, w = t >> 6;
    const int bB = (w << 10)
                 | (((n >> 3) & 1) << 5) | (((n >> 1) & 1) << 4)
                 | (((n >> 5) & 1) << 3) | ((n & 1) << 2)
                 | (((n >> 4) & 1) << 1) | ((n >> 2) & 1);

    // ---- stage 1: embedding (SiLU) ----
    if (t < NQ) {
        float s = benc[t];
        #pragma unroll
        for (int k = 0; k < NQ; ++k) s += cond[b*NQ + k] * Wenc[t*NQ + k];
        embS[t] = s / (1.0f + __expf(-s));
    }
    __syncthreads();

    // ---- stage 2: per-wire 2-vectors after encoding + layer 0 (fp32) ----
    if (t < NQ) {
        float v = embS[t];
        float s, c;
        sincosf(0.5f*v, &s, &c);
        f2 a0 = (f2){c*c,  s*s};
        f2 a1 = (f2){s*c, -s*c};
        f4 va = G0[t*2], vb = G0[t*2 + 1];
        f2 u00 = (f2){va.x, va.y}, u01 = (f2){va.z, va.w};
        f2 u10 = (f2){vb.x, vb.y}, u11 = (f2){vb.z, vb.w};
        qv[t][0] = cmul(u00, a0) + cmul(u01, a1);
        qv[t][1] = cmul(u10, a0) + cmul(u11, a1);
    }
    __syncthreads();

    // ---- stage 3: partial-product tables (fp32) ----
    if (t < 128) {
        f2 p = qv[0][(t >> 6) & 1];
        #pragma unroll
        for (int ww = 1; ww <= 6; ++ww) p = cmul(p, qv[ww][(t >> (6 - ww)) & 1]);
        Phi[t] = p;
    } else if (t < 256) {
        const int j = t - 128;
        f2 p = qv[7][(j >> 6) & 1];
        #pragma unroll
        for (int ww = 8; ww <= 13; ++ww) p = cmul(p, qv[ww][(j >> (13 - ww)) & 1]);
        Plo[j] = p;
    }
    __syncthreads();

    // ---- stage 4: build product state in f16 planes (view A), CZ0 fused ----
    h2 hr[8], hi[8];
    {
        f2 plo = Plo[((n & 7) << 4) | w];
        #pragma unroll
        for (int k = 0; k < 8; ++k) {
            const int l0 = 2*k, l1 = 2*k + 1;
            const int e0 = (l0 << 10) | (n << 4) | w;
            const int e1 = (l1 << 10) | (n << 4) | w;
            f2 a0 = cmul(Phi[(l0 << 3) | (n >> 3)], plo) * czsgn(e0);
            f2 a1 = cmul(Phi[(l1 << 3) | (n >> 3)], plo) * czsgn(e1);
            hr[k] = __floats2half2_rn(a0.x, a1.x);
            hi[k] = __floats2half2_rn(a0.y, a1.y);
        }
    }

    // ---- stage 5: 6 half-layers, f16-plane gates ----
    #pragma unroll
    for (int h = 0; h < 6; ++h) {
        const h2* __restrict__ g = Gh + h*7*8;
        reg_gate_h<4>(hr, hi, g + 0*8);     // l-mask 8
        reg_gate_h<2>(hr, hi, g + 1*8);     // l-mask 4
        reg_gate_h<1>(hr, hi, g + 2*8);     // l-mask 2
        pair_gate_h(hr, hi, g + 3*8);       // l-mask 1
        lane_gate_h<8>(hr, hi, g + 4*8, t);
        lane_gate_h<2>(hr, hi, g + 5*8, t);
        lane_gate_h<1>(hr, hi, g + 6*8, t);
        if (h == 1)      cz_B_h(hr, hi, t); // CZ after layer 1 (view B)
        else if (h == 3) cz_A_h(hr, hi, t); // CZ after layer 2 (view A)
        if (h == 0 || h == 4) {             // remap A -> B
            #pragma unroll
            for (int k = 0; k < 8; ++k) {
                st[t + ((2*k)   << 10)] = __halves2half2(__low2half(hr[k]),  __low2half(hi[k]));
                st[t + ((2*k+1) << 10)] = __halves2half2(__high2half(hr[k]), __high2half(hi[k]));
            }
            __syncthreads();
            #pragma unroll
            for (int k = 0; k < 8; ++k) {
                h2 w0 = st[bB + ((2*k)   << 6)];
                h2 w1 = st[bB + ((2*k+1) << 6)];
                hr[k] = __halves2half2(__low2half(w0),  __low2half(w1));
                hi[k] = __halves2half2(__high2half(w0), __high2half(w1));
            }
        } else if (h == 2) {                // remap B -> A
            #pragma unroll
            for (int k = 0; k < 8; ++k) {
                st[bB + ((2*k)   << 6)] = __halves2half2(__low2half(hr[k]),  __low2half(hi[k]));
                st[bB + ((2*k+1) << 6)] = __halves2half2(__high2half(hr[k]), __high2half(hi[k]));
            }
            __syncthreads();
            #pragma unroll
            for (int k = 0; k < 8; ++k) {
                h2 w0 = st[t + ((2*k)   << 10)];
                h2 w1 = st[t + ((2*k+1) << 10)];
                hr[k] = __halves2half2(__low2half(w0),  __low2half(w1));
                hi[k] = __halves2half2(__high2half(w0), __high2half(w1));
            }
        }
    }
    // (CZ after layer 3 dropped: |psi|^2 invariant)

    // ---- fused probability reduction (view B, fp32 accumulate) ----
    float SU, Q10, Q11, Q12, Q13;
    {
        SU = Q10 = Q11 = Q12 = Q13 = 0.f;
        #pragma unroll
        for (int k = 0; k < 8; ++k) {
            float2 fr = __half22float2(hr[k]);
            float2 fi = __half22float2(hi[k]);
            float pl = fr.x*fr.x + fi.x*fi.x;
            float ph = fr.y*fr.y + fi.y*fi.y;
            float g2 = pl + ph;
            SU  += g2;
            Q13 += pl - ph;                 // l0
            Q10 += (k & 4) ? -g2 : g2;      // l3
            Q11 += (k & 2) ? -g2 : g2;      // l2
            Q12 += (k & 1) ? -g2 : g2;      // l1
        }
    }

    // ---- stage 6: reduce to 14 expectations, layernorm (fp32) ----
    // View-B thread-uniform sign bits: q0:t9 q1:t8 q2:t7 q3:t6 q4:t3 q5:t1
    // q6:t5 q7:t0 q8:t4 q9:t2.
    {
        const int lane = t & 63, wv = t >> 6;
        const int sbit[10] = {9, 8, 7, 6, 3, 1, 5, 0, 4, 2};
        #pragma unroll
        for (int ww = 0; ww < NQ; ++ww) {
            float v;
            if      (ww == 10) v = Q10;
            else if (ww == 11) v = Q11;
            else if (ww == 12) v = Q12;
            else if (ww == 13) v = Q13;
            else               v = ((t >> sbit[ww]) & 1) ? -SU : SU;
            #pragma unroll
            for (int off = 32; off > 0; off >>= 1) v += __shfl_down(v, off, 64);
            if (lane == 0) wred[wv][ww] = v;
        }
    }
    __syncthreads();
    if (t < NQ) {
        float s = 0.f;
        #pragma unroll
        for (int k = 0; k < 16; ++k) s += wred[k][t];
        lat[t] = s;
    }
    __syncthreads();
    if (t < NQ) {
        float mu = 0.f;
        #pragma unroll
        for (int k = 0; k < NQ; ++k) mu += lat[k];
        mu *= (1.0f / NQ);
        float var = 0.f;
        #pragma unroll
        for (int k = 0; k < NQ; ++k) { float dv = lat[k] - mu; var += dv*dv; }
        var *= (1.0f / NQ);
        out[b*NQ + t] = (lat[t] - mu) * rsqrtf(var + 1e-5f);
    }
}

extern "C" void kernel_launch(void* const* d_in, const int* in_sizes, int n_in,
                              void* d_out, int out_size, void* d_ws, size_t ws_size,
                              hipStream_t stream)
{
    (void)n_in; (void)ws_size; (void)out_size;
    const float* cond = (const float*)d_in[0];
    const float* Wenc = (const float*)d_in[1];
    const float* benc = (const float*)d_in[2];
    const float* wts  = (const float*)d_in[3];
    float* out = (float*)d_out;
    h2* Gh = (h2*)d_ws;                          // 336 h2 = 1344 B
    f4* G0 = (f4*)((char*)d_ws + 2048);          // 28 f4 = 448 B
    const int B = in_sizes[0] / NQ;              // 256
    qlg_prep<<<dim3(1), dim3(64), 0, stream>>>(wts, Gh, G0);
    qlg_kernel<<<dim3(B), dim3(1024), 0, stream>>>(cond, Wenc, benc, Gh, G0, out);
}